// Round 5
// baseline (547.441 us; speedup 1.0000x reference)
//
#include <hip/hip_runtime.h>

// Problem constants
#define N_    8
#define TP_   2048
#define E_    4096
#define S_    8
#define C_    64
#define T_    16384      // TP_*S_
#define TS_   131072     // T_*S_
#define OUTW  17         // V+1
#define OUT_ELEMS 17825792  // N_*TS_*OUTW
#define F4_PER_N 557056     // 16384 rows * 34 float4 per row
#define F4_TOTAL 4456448    // OUT_ELEMS/4

typedef __attribute__((ext_vector_type(8))) short short8;
typedef __attribute__((ext_vector_type(4))) float float4v;

static __device__ __forceinline__ unsigned short f2bf(float f) {
    unsigned int u = __builtin_bit_cast(unsigned int, f);
    u += 0x7FFFu + ((u >> 16) & 1u);   // round-to-nearest-even
    return (unsigned short)(u >> 16);
}

// ---------------------------------------------------------------------------
// prep: LDS-tiled transpose W1 [4096][512] fp32 -> Bb [512][4096] bf16
//   Bb row index = c*8+s; block (0,0) also computes K2.
// ---------------------------------------------------------------------------
__global__ __launch_bounds__(256) void prep_kernel(
    const float* __restrict__ W1, const float* __restrict__ b1,
    const float* __restrict__ W2, const float* __restrict__ b2,
    unsigned short* __restrict__ Bb, float* __restrict__ K2)
{
    __shared__ float tile[64][65];
    const int tid = threadIdx.x;
    if (blockIdx.x == 0 && blockIdx.y == 0 && tid < 8) {
        int s2 = tid;
        float acc = b2[0];
        for (int c = 0; c < C_; ++c) acc += b1[c] * W2[c * S_ + s2];
        K2[s2] = acc;
    }
    const int e0  = blockIdx.x * 64;   // 64 e-tiles
    const int cs0 = blockIdx.y * 64;   // 8 cs-tiles
    {
        int rr = tid >> 2;        // e row 0..63
        int c4 = tid & 3;
        for (int i = 0; i < 4; ++i) {
            int f4 = c4 + i * 4;  // 0..15
            float4 v = *(const float4*)&W1[(size_t)(e0 + rr) * 512 + cs0 + f4 * 4];
            tile[f4 * 4 + 0][rr] = v.x;
            tile[f4 * 4 + 1][rr] = v.y;
            tile[f4 * 4 + 2][rr] = v.z;
            tile[f4 * 4 + 3][rr] = v.w;
        }
    }
    __syncthreads();
    {
        int cs  = tid >> 2;       // 0..63
        int seg = tid & 3;        // 16 shorts each
        for (int h = 0; h < 2; ++h) {
            short8 o;
#pragma unroll
            for (int j = 0; j < 8; ++j)
                o[j] = (short)f2bf(tile[cs][seg * 16 + h * 8 + j]);
            *(short8*)&Bb[(size_t)(cs0 + cs) * E_ + e0 + seg * 16 + h * 8] = o;
        }
    }
}

// ---------------------------------------------------------------------------
// compact: per (n,s) block; int4 value loads; wave-shuffle scan; 64-ary
// argmax search; builds gathered row lists + global tile work-list.
// ---------------------------------------------------------------------------
__global__ __launch_bounds__(256) void compact_kernel(
    const int* __restrict__ value, const int* __restrict__ depth,
    int* __restrict__ cnt_ns, int* __restrict__ cnt_total,
    int* __restrict__ tile_counter, int* __restrict__ tiles,
    int* __restrict__ sel_tp, int* __restrict__ sel_j)
{
    const int g = blockIdx.x;          // n*8 + s
    const int n = g >> 3;
    const int s = g & 7;
    const int tid  = threadIdx.x;
    const int lane = tid & 63;
    const int wv   = tid >> 6;

    __shared__ int idx_sh;
    __shared__ unsigned int wsum[4];

    const int* d = depth + (size_t)n * T_;
    if (tid < 64) {                    // wave 0: 64-ary search, 3 rounds
        int maxv = d[T_ - 1];
        int lower = 0, upper = T_ - 1;
        for (int rnd = 0; rnd < 3; ++rnd) {
            int span = upper - lower;
            int step = (span + 63) >> 6;
            if (step < 1) step = 1;
            int p = lower + lane * step;
            if (p > upper) p = upper;
            unsigned long long b = __ballot(d[p] == maxv);
            int f = __ffsll((long long)b) - 1;   // ballot never 0: d[upper]==maxv
            int nu = lower + f * step; if (nu > upper) nu = upper;
            int nl = (f == 0) ? lower : lower + (f - 1) * step + 1;
            if (nl > nu) nl = nu;
            lower = nl; upper = nu;
        }
        if (lane == 0) idx_sh = lower;
    }
    __syncthreads();
    const int idx = idx_sh;
    const int4* val4 = (const int4*)(value + (size_t)n * T_);

    const int b4 = tid * 16;           // int4 base; covers t in [tid*64, tid*64+64)
    unsigned int packed = 0;           // (any-count << 16) | s-residue count
    for (int i = 0; i < 16; ++i) {
        int4 v = val4[b4 + i];
        int t = (b4 + i) * 4;
        if (t + 0 < idx && v.x == 2) { packed += 0x10000u; if (((t + 0) & 7) == s) packed += 1u; }
        if (t + 1 < idx && v.y == 2) { packed += 0x10000u; if (((t + 1) & 7) == s) packed += 1u; }
        if (t + 2 < idx && v.z == 2) { packed += 0x10000u; if (((t + 2) & 7) == s) packed += 1u; }
        if (t + 3 < idx && v.w == 2) { packed += 0x10000u; if (((t + 3) & 7) == s) packed += 1u; }
    }
    unsigned int inc = packed;
#pragma unroll
    for (int off = 1; off < 64; off <<= 1) {
        unsigned int u = __shfl_up((int)inc, off, 64);
        if (lane >= off) inc += u;
    }
    if (lane == 63) wsum[wv] = inc;
    __syncthreads();
    unsigned int woff = 0;
    for (int ww = 0; ww < wv; ++ww) woff += wsum[ww];
    unsigned int excl = woff + inc - packed;
    int any_rank = (int)(excl >> 16);
    int s_rank   = (int)(excl & 0xFFFFu);
    for (int i = 0; i < 16; ++i) {
        int4 v = val4[b4 + i];
        int vv[4] = { v.x, v.y, v.z, v.w };
        int t = (b4 + i) * 4;
#pragma unroll
        for (int e = 0; e < 4; ++e) {
            int tt = t + e;
            if (tt < idx && vv[e] == 2) {
                if ((tt & 7) == s) {
                    sel_tp[g * 2048 + s_rank] = tt >> 3;
                    sel_j [g * 2048 + s_rank] = any_rank;
                    ++s_rank;
                }
                ++any_rank;
            }
        }
    }
    if (tid == 255) {
        unsigned int tot = woff + inc;
        int cnt = (int)(tot & 0xFFFFu);
        cnt_ns[g] = cnt;
        if (s == 0) cnt_total[n] = (int)(tot >> 16);
        int ntl = (cnt + 63) >> 6;
        int base = atomicAdd(tile_counter, ntl);
        for (int i = 0; i < ntl; ++i) tiles[base + i] = (g << 8) | i;
    }
}

// ---------------------------------------------------------------------------
// fill: vectorized b2*W3 pattern; skips rows j < cnt_total[n] (combine writes)
// ---------------------------------------------------------------------------
__global__ __launch_bounds__(256) void fill_kernel(
    float* __restrict__ out, const float* __restrict__ W3,
    const float* __restrict__ b2, const int* __restrict__ cnt_total)
{
    __shared__ float pat[136];
    const int tid = threadIdx.x;
    if (tid < 136) pat[tid] = b2[0] * W3[tid % OUTW];
    __syncthreads();
    int i4 = blockIdx.x * 256 + tid;          // < F4_TOTAL exactly
    int n   = i4 / F4_PER_N;
    int rem = i4 - n * F4_PER_N;
    int j   = rem / 34;                       // output row within sample
    if (j >= cnt_total[n]) {
        int o = (rem - j * 34) * 4;
        float4 v = { pat[o], pat[o + 1], pat[o + 2], pat[o + 3] };
        *(float4*)&out[(size_t)i4 * 4] = v;
    }
}

// ---------------------------------------------------------------------------
// main: BARRIER-FREE gathered GEMM. Each wave loads A directly from global x
// in MFMA fragment layout (lane m -> row tp_l[w*16+m], q-lanes cover 128 B
// contiguous per row; every byte read exactly once) and B directly from the
// bf16 Bb (L2/L3 resident). No LDS / no __syncthreads in the K-loop — waves
// free-run, depth-4 register pipeline (constant unroll indices only; runtime
// indices spilled to scratch in round 3). Split-K x2: virtual tile = (tile,
// k-half); partial y2 (no K2) written to ws, combined later.
// ---------------------------------------------------------------------------
__global__ __launch_bounds__(256) void main_kernel(
    const float* __restrict__ x, const unsigned short* __restrict__ Bb,
    const int* __restrict__ tile_counter, const int* __restrict__ tiles,
    const int* __restrict__ cnt_ns, const int* __restrict__ sel_tp,
    const float* __restrict__ W2, float* __restrict__ y2_part)
{
    __shared__ float Cl[64][68];
    __shared__ int tp_l[64];
    __shared__ float W2s[C_ * S_];

    const int tid  = threadIdx.x;
    const int lane = tid & 63;
    const int w    = tid >> 6;        // wave id: rows [w*16, w*16+16)
    const int m    = lane & 15;
    const int q    = lane >> 4;

    for (int i = tid; i < C_ * S_; i += 256) W2s[i] = W2[i];

    const int nvt = 2 * (*tile_counter);

    for (int vt = blockIdx.x; vt < nvt; vt += gridDim.x) {
        const int ti = vt >> 1;
        const int kh = vt & 1;                 // k-half: [kh*2048, kh*2048+2048)
        const int ent = tiles[ti];
        const int g  = ent >> 8;
        const int n  = g >> 3;
        const int s  = g & 7;
        const int m0 = (ent & 255) * 64;
        const int cnt = cnt_ns[g];

        __syncthreads();    // previous iteration's Cl reads / tp_l use done
        if (tid < 64) {
            int idx = m0 + tid;
            tp_l[tid] = (idx < cnt) ? sel_tp[g * 2048 + idx] : 0;
        }
        __syncthreads();

        const float* abase = x + ((size_t)n * TP_ + tp_l[w * 16 + m]) * E_
                               + kh * 2048 + q * 8;
        const unsigned short* bb0 = Bb + ((size_t)(( 0 + m) * 8 + s)) * E_ + kh * 2048 + q * 8;
        const unsigned short* bb1 = Bb + ((size_t)((16 + m) * 8 + s)) * E_ + kh * 2048 + q * 8;
        const unsigned short* bb2 = Bb + ((size_t)((32 + m) * 8 + s)) * E_ + kh * 2048 + q * 8;
        const unsigned short* bb3 = Bb + ((size_t)((48 + m) * 8 + s)) * E_ + kh * 2048 + q * 8;

        // depth-4 register pipeline (indices constant after unroll)
        float4 aLo[4], aHi[4];
        short8 bf0[4], bf1[4], bf2[4], bf3[4];
#pragma unroll
        for (int u = 0; u < 4; ++u) {
            aLo[u] = *(const float4*)(abase + u * 32);
            aHi[u] = *(const float4*)(abase + u * 32 + 4);
            bf0[u] = *(const short8*)(bb0 + u * 32);
            bf1[u] = *(const short8*)(bb1 + u * 32);
            bf2[u] = *(const short8*)(bb2 + u * 32);
            bf3[u] = *(const short8*)(bb3 + u * 32);
        }

        float4v acc0 = (float4v){0.f,0.f,0.f,0.f};
        float4v acc1 = (float4v){0.f,0.f,0.f,0.f};
        float4v acc2 = (float4v){0.f,0.f,0.f,0.f};
        float4v acc3 = (float4v){0.f,0.f,0.f,0.f};

        for (int st = 0; st < 64; st += 4) {
#pragma unroll
            for (int u = 0; u < 4; ++u) {
                short8 a;
                a[0] = (short)f2bf(aLo[u].x); a[1] = (short)f2bf(aLo[u].y);
                a[2] = (short)f2bf(aLo[u].z); a[3] = (short)f2bf(aLo[u].w);
                a[4] = (short)f2bf(aHi[u].x); a[5] = (short)f2bf(aHi[u].y);
                a[6] = (short)f2bf(aHi[u].z); a[7] = (short)f2bf(aHi[u].w);
                acc0 = __builtin_amdgcn_mfma_f32_16x16x32_bf16(a, bf0[u], acc0, 0, 0, 0);
                acc1 = __builtin_amdgcn_mfma_f32_16x16x32_bf16(a, bf1[u], acc1, 0, 0, 0);
                acc2 = __builtin_amdgcn_mfma_f32_16x16x32_bf16(a, bf2[u], acc2, 0, 0, 0);
                acc3 = __builtin_amdgcn_mfma_f32_16x16x32_bf16(a, bf3[u], acc3, 0, 0, 0);
                if (st + 4 + u < 64) {
                    const int ko = (st + 4 + u) * 32;
                    aLo[u] = *(const float4*)(abase + ko);
                    aHi[u] = *(const float4*)(abase + ko + 4);
                    bf0[u] = *(const short8*)(bb0 + ko);
                    bf1[u] = *(const short8*)(bb1 + ko);
                    bf2[u] = *(const short8*)(bb2 + ko);
                    bf3[u] = *(const short8*)(bb3 + ko);
                }
            }
        }

        // D layout: row = q*4+reg, col = lane&15 (m89-verified)
#pragma unroll
        for (int rr = 0; rr < 4; ++rr) {
            Cl[w * 16 + q * 4 + rr][ 0 + m] = acc0[rr];
            Cl[w * 16 + q * 4 + rr][16 + m] = acc1[rr];
            Cl[w * 16 + q * 4 + rr][32 + m] = acc2[rr];
            Cl[w * 16 + q * 4 + rr][48 + m] = acc3[rr];
        }
        __syncthreads();

        // partial y2 (no K2): y2_part[ti*1024 + kh*512 + row*8 + s2]
        for (int task = tid; task < 512; task += 256) {
            int row = task >> 3;
            int s2  = task & 7;
            float y2 = 0.f;
#pragma unroll
            for (int c = 0; c < C_; ++c) y2 += Cl[row][c] * W2s[c * S_ + s2];
            y2_part[(size_t)ti * 1024 + kh * 512 + task] = y2;
        }
    }
}

// ---------------------------------------------------------------------------
// combine: y2 = part0 + part1 + K2; out row = y2 * W3 (coalesced f4 writes)
// ---------------------------------------------------------------------------
__global__ __launch_bounds__(256) void combine_kernel(
    const int* __restrict__ tile_counter, const int* __restrict__ tiles,
    const int* __restrict__ cnt_ns, const int* __restrict__ sel_j,
    const float* __restrict__ y2_part, const float* __restrict__ K2,
    const float* __restrict__ W3, float* __restrict__ out)
{
    __shared__ float y2s[64][8];
    __shared__ int j_l[64];
    __shared__ float W3s[OUTW];
    __shared__ float K2s[S_];

    const int tid = threadIdx.x;
    if (tid < OUTW) W3s[tid] = W3[tid];
    if (tid < S_)   K2s[tid] = K2[tid];

    const int ntile = *tile_counter;

    for (int ti = blockIdx.x; ti < ntile; ti += gridDim.x) {
        const int ent = tiles[ti];
        const int g  = ent >> 8;
        const int n  = g >> 3;
        const int m0 = (ent & 255) * 64;
        const int rows = min(64, cnt_ns[g] - m0);

        __syncthreads();
        if (tid < 64) j_l[tid] = (tid < rows) ? sel_j[g * 2048 + m0 + tid] : 0;
        for (int task = tid; task < 512; task += 256) {
            y2s[task >> 3][task & 7] = y2_part[(size_t)ti * 1024 + task]
                                     + y2_part[(size_t)ti * 1024 + 512 + task]
                                     + K2s[task & 7];
        }
        __syncthreads();

        for (int task = tid; task < 64 * 34; task += 256) {
            int row = task / 34;
            int f   = task - row * 34;
            if (row < rows) {
                float4 v;
                float* vp = (float*)&v;
#pragma unroll
                for (int e = 0; e < 4; ++e) {
                    int idx = f * 4 + e;
                    int s2  = (idx * 241) >> 12;   // idx/17 for idx<136
                    int vi  = idx - s2 * OUTW;
                    vp[e] = y2s[row][s2] * W3s[vi];
                }
                *(float4*)&out[((size_t)n * TS_ + (size_t)j_l[row] * S_) * OUTW + f * 4] = v;
            }
        }
    }
}

// ---------------------------------------------------------------------------
extern "C" void kernel_launch(void* const* d_in, const int* in_sizes, int n_in,
                              void* d_out, int out_size, void* d_ws, size_t ws_size,
                              hipStream_t stream) {
    const float* x     = (const float*)d_in[0];
    const int*   value = (const int*)d_in[1];
    const int*   depth = (const int*)d_in[2];
    // d_in[3] = pos (unused by reference)
    const float* W1    = (const float*)d_in[4];
    const float* b1    = (const float*)d_in[5];
    const float* W2    = (const float*)d_in[6];
    const float* b2    = (const float*)d_in[7];
    const float* W3    = (const float*)d_in[8];
    float* out = (float*)d_out;

    // workspace layout (~13.3 MB)
    unsigned short* Bb = (unsigned short*)d_ws;            // 512*4096 bf16 = 4 MB
    float* K2          = (float*)(Bb + 512 * 4096);        // 8
    int* tile_counter  = (int*)(K2 + 8);                   // 1
    int* cnt_ns        = tile_counter + 1;                 // 64
    int* cnt_total     = cnt_ns + 64;                      // 8
    int* tiles         = cnt_total + 8;                    // 2048 max
    int* sel_tp        = tiles + 2048;                     // 64*2048
    int* sel_j         = sel_tp + 64 * 2048;               // 64*2048
    float* y2_part     = (float*)(sel_j + 64 * 2048);      // 2048*1024 = 8 MB

    hipMemsetAsync(tile_counter, 0, sizeof(int), stream);

    dim3 pgrid(64, 8);
    prep_kernel<<<pgrid, 256, 0, stream>>>(W1, b1, W2, b2, Bb, K2);
    compact_kernel<<<64, 256, 0, stream>>>(value, depth, cnt_ns, cnt_total,
                                           tile_counter, tiles, sel_tp, sel_j);
    fill_kernel<<<F4_TOTAL / 256, 256, 0, stream>>>(out, W3, b2, cnt_total);
    main_kernel<<<1024, 256, 0, stream>>>(x, Bb, tile_counter, tiles, cnt_ns,
                                          sel_tp, W2, y2_part);
    combine_kernel<<<512, 256, 0, stream>>>(tile_counter, tiles, cnt_ns, sel_j,
                                            y2_part, K2, W3, out);
}